// Round 3
// baseline (107.517 us; speedup 1.0000x reference)
//
#include <hip/hip_runtime.h>
#include <hip/hip_bf16.h>

// Problem geometry (fixed by the reference)
#define BD   4
#define SD   8
#define LSEC 256
#define LL   254
#define DD   768
#define MAXS 100
#define TT   (SD*LL)   // 2032

// Flat output offsets (float32 elements, reference return order)
#define OFF_SF  0LL                       // sentence_feature [4,100,768]   307200
#define OFF_TM  307200LL                  // tran_mask        [4,2032,8]     65024
#define OFF_TMS 372224LL                  // tran_mask_sec    [4,100,8]       3200
#define OFF_SMF 375424LL                  // sentence_mask_full [4,2032,2032] 16516096
#define OFF_SEC (375424LL + 16516096LL)   // section_mask_full  [4,2032,2032] 16516096
#define OFF_LOG 33407616LL                // logits1 [4,2]

// Fused kernel 1 partition: mask blocks then pool blocks
#define ROWS_PER_BLK 4
#define CHUNKS ((LL + ROWS_PER_BLK - 1) / ROWS_PER_BLK)   // 64
#define NMASK (BD*SD*CHUNKS)    // 2048
#define NPOOL (BD*MAXS*3)       // 1200

// ---------------------------------------------------------------------------
// Kernel 1 (lean): mask rows + per-sentence max pooling. LDS <= 2.1 KB.
// ---------------------------------------------------------------------------
struct LeanSMem {
    int   ids[LL];
    float am[LL];
    int   sf, sl;
};

__global__ __launch_bounds__(256) void lean_kernel(
    const float* __restrict__ atf,     // [32][256][768]
    const int*   __restrict__ att,     // [32][256]
    const int*   __restrict__ ids_g,   // [B][T], nondecreasing runs 1..100
    float* __restrict__ pooled,        // [400][768] ws
    float* __restrict__ out)
{
    __shared__ LeanSMem sm;
    const int blk = blockIdx.x;
    const int tid = threadIdx.x;

    if (blk < NMASK) {
        // ---------- mask: 4 rows of both big masks for (b, j1, chunk) ------
        const int sec   = blk >> 6;          // 0..31
        const int chunk = blk & 63;          // 0..63
        const int b  = sec >> 3;
        const int j1 = sec & 7;
        for (int i = tid; i < LL; i += 256) {
            sm.ids[i] = ids_g[b*TT + j1*LL + i];
            sm.am[i]  = (float)att[(b*SD + j1)*LSEC + 1 + i];
        }
        __syncthreads();
        const int cstart = j1 * LL;
        #pragma unroll
        for (int rr = 0; rr < ROWS_PER_BLK; ++rr) {
            const int i1 = chunk * ROWS_PER_BLK + rr;
            if (i1 >= LL) break;
            const int t1   = j1*LL + i1;
            const long long row = (long long)b*TT + t1;
            const int   myid = sm.ids[i1];
            const float am1  = sm.am[i1];

            if (tid < SD)
                out[OFF_TM + row*SD + tid] = (tid == j1) ? 1.f : 0.f;

            float* row4 = out + OFF_SMF + row * TT;
            float* row5 = out + OFF_SEC + row * TT;
            for (int fq = tid; fq < TT/4; fq += 256) {
                int c = fq * 4;
                float4 v4, v5;
                float* pv4 = (float*)&v4; float* pv5 = (float*)&v5;
                #pragma unroll
                for (int u = 0; u < 4; ++u) {
                    int i2 = c + u - cstart;
                    bool in = (i2 >= 0) & (i2 < LL);
                    int ii = in ? i2 : 0;
                    pv4[u] = in ? ((sm.ids[ii] == myid) ? 1.f : 0.f) : 0.f;
                    pv5[u] = in ? (sm.am[ii] * am1) : 0.f;
                }
                *(float4*)&row4[c] = v4;
                *(float4*)&row5[c] = v5;
            }
        }
    } else {
        // ---------- pool: (sentence, d-chunk) max over contiguous range ----
        const int p    = blk - NMASK;
        const int sent = p % (BD*MAXS);
        const int d0   = (p / (BD*MAXS)) << 8;   // 0,256,512
        const int b    = sent / MAXS;
        const int sid  = sent % MAXS + 1;

        if (tid == 0) { sm.sf = TT; sm.sl = -1; }
        __syncthreads();
        int lf = TT, lm = -1;
        for (int t = tid; t < TT; t += 256) {
            if (ids_g[b*TT + t] == sid) { lf = min(lf, t); lm = max(lm, t); }
        }
        atomicMin(&sm.sf, lf);
        atomicMax(&sm.sl, lm);
        __syncthreads();
        const int f = sm.sf, l = sm.sl;

        float m = 0.0f;                    // absent sentence id -> zero
        if (l >= 0) {
            float m0 = -INFINITY, m1 = -INFINITY, m2 = -INFINITY, m3 = -INFINITY;
            for (int t = f; t <= l; t += 4) {
                int t1 = min(t + 1, l), t2 = min(t + 2, l), t3 = min(t + 3, l);
                long long r0 = ((long long)(b*SD + t  / LL) * LSEC + 1 + t  % LL) * DD + d0 + tid;
                long long r1 = ((long long)(b*SD + t1 / LL) * LSEC + 1 + t1 % LL) * DD + d0 + tid;
                long long r2 = ((long long)(b*SD + t2 / LL) * LSEC + 1 + t2 % LL) * DD + d0 + tid;
                long long r3 = ((long long)(b*SD + t3 / LL) * LSEC + 1 + t3 % LL) * DD + d0 + tid;
                m0 = fmaxf(m0, atf[r0]);
                m1 = fmaxf(m1, atf[r1]);
                m2 = fmaxf(m2, atf[r2]);
                m3 = fmaxf(m3, atf[r3]);
            }
            m = fmaxf(fmaxf(m0, m1), fmaxf(m2, m3));
        }
        pooled[(long long)sent * DD + d0 + tid] = m;
    }
}

// ---------------------------------------------------------------------------
// Kernel 2 (fat): prep (4 blocks) + gemm (150 blocks)
// ---------------------------------------------------------------------------
union FatSMem {
    struct { float As[16][68]; float Ws[128][68]; } g;                 // 39168 B
    struct { int ids[TT]; int counts[SD]; int starts[SD]; float red[256]; } p;
};

__global__ __launch_bounds__(256) void fat_kernel(
    const float* __restrict__ pf,      // pooled_feature [32][768]
    const int*   __restrict__ ids_g,   // [B][T]
    const float* __restrict__ Wg2,     // [768][768] row-major [e][d]
    const float* __restrict__ Wcls,    // [2][768]
    const float* __restrict__ bcls,    // [2]
    const float* __restrict__ pooled,  // [400][768] ws
    float* __restrict__ out)
{
    __shared__ FatSMem sm;
    const int blk = blockIdx.x;
    const int tid = threadIdx.x;

    if (blk < BD) {
        // ---------------- prep: tran_mask_sec + logits1 for doc b ----------
        const int b = blk;
        for (int t = tid; t < TT; t += 256) sm.p.ids[t] = ids_g[b*TT + t];
        if (tid < SD) sm.p.counts[tid] = 0;
        __syncthreads();
        for (int t = tid; t < TT; t += 256) {
            int j = t / LL;
            bool bnd = (t % LL == 0) || (sm.p.ids[t] != sm.p.ids[t-1]);
            if (bnd) atomicAdd(&sm.p.counts[j], 1);
        }
        __syncthreads();
        if (tid == 0) {
            int acc = 0;
            for (int j = 0; j < SD; ++j) { sm.p.starts[j] = acc; acc += sm.p.counts[j]; }
        }
        __syncthreads();
        for (int idx = tid; idx < MAXS*SD; idx += 256) {
            int r = idx / SD, j = idx % SD;
            float v = (r >= sm.p.starts[j] && r < sm.p.starts[j] + sm.p.counts[j]) ? 1.0f : 0.0f;
            out[OFF_TMS + (long long)b*(MAXS*SD) + idx] = v;
        }
        float acc0 = 0.f, acc1 = 0.f;
        #pragma unroll
        for (int k = 0; k < 3; ++k) {
            int d = tid + k*256;
            float mv = pf[(b*SD)*DD + d];
            #pragma unroll
            for (int j = 1; j < SD; ++j) mv = fmaxf(mv, pf[(b*SD + j)*DD + d]);
            acc0 += mv * Wcls[d];
            acc1 += mv * Wcls[DD + d];
        }
        sm.p.red[tid] = acc0; __syncthreads();
        for (int off = 128; off > 0; off >>= 1) { if (tid < off) sm.p.red[tid] += sm.p.red[tid+off]; __syncthreads(); }
        float l0 = sm.p.red[0];
        __syncthreads();
        sm.p.red[tid] = acc1; __syncthreads();
        for (int off = 128; off > 0; off >>= 1) { if (tid < off) sm.p.red[tid] += sm.p.red[tid+off]; __syncthreads(); }
        if (tid == 0) {
            out[OFF_LOG + b*2 + 0] = l0          + bcls[0];
            out[OFF_LOG + b*2 + 1] = sm.p.red[0] + bcls[1];
        }
    } else {
        // ---------------- gemm: sentence_feature = pooled @ Wg2^T ----------
        const int g  = blk - BD;
        const int r0 = (g % 25) * 16;
        const int e0 = (g / 25) * 128;
        const int er = tid & 31;
        const int sr = tid >> 5;       // 0..7
        float acc[2][4] = {{0.f,0.f,0.f,0.f},{0.f,0.f,0.f,0.f}};

        for (int k0 = 0; k0 < DD; k0 += 64) {
            {   // stage A: 16x64 = 256 float4
                int i = tid >> 4, c4 = (tid & 15) * 4;
                *(float4*)&sm.g.As[i][c4] = *(const float4*)&pooled[(long long)(r0 + i)*DD + k0 + c4];
            }
            #pragma unroll
            for (int it = 0; it < 8; ++it) {   // stage W: 128x64 = 2048 float4
                int idx = tid + it*256;
                int row = idx >> 4, c4 = (idx & 15) * 4;
                *(float4*)&sm.g.Ws[row][c4] = *(const float4*)&Wg2[(long long)(e0 + row)*DD + k0 + c4];
            }
            __syncthreads();
            #pragma unroll
            for (int k = 0; k < 64; k += 4) {
                float4 a0 = *(float4*)&sm.g.As[2*sr][k];
                float4 a1 = *(float4*)&sm.g.As[2*sr+1][k];
                #pragma unroll
                for (int c = 0; c < 4; ++c) {
                    float4 w = *(float4*)&sm.g.Ws[er + 32*c][k];
                    acc[0][c] += a0.x*w.x + a0.y*w.y + a0.z*w.z + a0.w*w.w;
                    acc[1][c] += a1.x*w.x + a1.y*w.y + a1.z*w.z + a1.w*w.w;
                }
            }
            __syncthreads();
        }
        #pragma unroll
        for (int si = 0; si < 2; ++si)
            #pragma unroll
            for (int c = 0; c < 4; ++c)
                out[OFF_SF + (long long)(r0 + 2*sr + si)*DD + e0 + er + 32*c] = acc[si][c];
    }
}

// ---------------------------------------------------------------------------
extern "C" void kernel_launch(void* const* d_in, const int* in_sizes, int n_in,
                              void* d_out, int out_size, void* d_ws, size_t ws_size,
                              hipStream_t stream)
{
    const float* atf  = (const float*)d_in[0];  // all_token_feature [32,256,768]
    const float* pf   = (const float*)d_in[1];  // pooled_feature    [32,768]
    const int*   att  = (const int*)  d_in[2];  // attention_mask    [32,256]
    const int*   ids  = (const int*)  d_in[3];  // sentence_mask     [4,8,254]
    const float* Wg2  = (const float*)d_in[4];  // W_g2 [768,768]
    const float* Wcls = (const float*)d_in[5];  // W_cls [2,768]
    const float* bcls = (const float*)d_in[6];  // b_cls [2]
    float* out = (float*)d_out;

    float* pooled = (float*)d_ws;               // [400][768] = 1.23 MB

    hipLaunchKernelGGL(lean_kernel, dim3(NMASK + NPOOL), dim3(256), 0, stream,
                       atf, att, ids, pooled, out);
    hipLaunchKernelGGL(fat_kernel, dim3(BD + 150), dim3(256), 0, stream,
                       pf, ids, Wg2, Wcls, bcls, pooled, out);
}